// Round 13
// baseline (1073.820 us; speedup 1.0000x reference)
//
#include <hip/hip_runtime.h>
#include <math.h>

// AddrNet eval forward: B=524288, D_MODEL=128, HID=16, N_BINS=256, DEPTH=8.
// Round 13: h-trajectory stays bit-exact no-FMA (R4 contract). Logits argmax
// via FMA SCREENING + certified exact fallback:
//   - screen: acc = fmaf(h_k, w_kj, acc) (16 insts/bin), track best+second.
//   - bound: |L_fma - L_nofma| <= ~8.3e-6*hmax (33 roundings, partials
//     <= 4*hmax since |W_out|<=0.25). EPS = 4e-5*hmax + 1e-5 (~5x safety).
//   - margin > EPS  => no-FMA argmax == FMA argmax (strict winner, provable).
//   - margin <= EPS => per-lane exact no-FMA 256-bin recompute (rare, ~5e-4),
//     sequential k-ascending, strict->, first-index ties — the R4 semantics.
// Input layer / embed add / MLP / np-Cephes-exp silu: unchanged exact no-FMA.

constexpr int BATCH  = 524288;
constexpr int DM     = 128;
constexpr int H      = 16;
constexpr int NB     = 256;
constexpr int DEPTHN = 8;

constexpr int BLOCK = 256;

__device__ __forceinline__ float np_expf(float x) {
    // Replica of numpy's SIMD float32 exp (Cephes scheme). Explicit FMAs:
    // part of the verified contract since R4 — do not change.
    const float LOG2E = 1.442695040888963407f;
    const float C1    = 0.693359375f;
    const float C2    = -2.12194440e-4f;
    float q = rintf(x * LOG2E);
    float r = __builtin_fmaf(q, -C1, x);
    r = __builtin_fmaf(q, -C2, r);
    float p = 1.9875691500E-4f;
    p = __builtin_fmaf(p, r, 1.3981999507E-3f);
    p = __builtin_fmaf(p, r, 8.3334519073E-3f);
    p = __builtin_fmaf(p, r, 4.1665795894E-2f);
    p = __builtin_fmaf(p, r, 1.6666665459E-1f);
    p = __builtin_fmaf(p, r, 5.0000001201E-1f);
    p = __builtin_fmaf(p, r * r, r);
    p = p + 1.0f;
    if (x > 88.72283935546875f)      return INFINITY;
    if (x < -103.97208404541015625f) return 0.0f;
    return ldexpf(p, (int)q);
}

// ---- prep:
//   ws[p*32 + k*2 + hh]  = W_out[k][2p+hh]   (pair-interleaved, p<128)
//   ws[4096 + i*16 + k]  = W_mlp[k][i]       (plain transpose)
__global__ void addrnet_prep_kernel(const float* __restrict__ W_out,
                                    const float* __restrict__ W_mlp,
                                    float* __restrict__ ws) {
    int t = threadIdx.x;                       // 256 threads, 1 block
    for (int i = t; i < NB * H; i += 256) {
        int p = i >> 5, r = i & 31;
        int k = r >> 1, hh = r & 1;
        ws[i] = W_out[k * NB + (2 * p + hh)];
    }
    {
        int ii = t >> 4, k = t & 15;
        ws[NB * H + ii * H + k] = W_mlp[k * H + ii];
    }
}

__global__ __launch_bounds__(BLOCK, 4) void addrnet_r13_kernel(
    const float* __restrict__ x,      // [B,128]
    const float* __restrict__ W_in,   // [128,16]
    const float* __restrict__ b_in,   // [16]
    const float* __restrict__ embed,  // [256,16]
    const float* __restrict__ b_mlp,  // [16]
    const float* __restrict__ b_out,  // [256]
    const float* __restrict__ ws,     // pair-WoutT ++ WmlpT
    int* __restrict__ out)            // [B,8] int32
{
#pragma clang fp contract(off)
    __shared__ __align__(16) float sEmb[NB * H];    // 16 KB, gather target

    for (int i = threadIdx.x; i < NB * H; i += BLOCK) sEmb[i] = embed[i];
    __syncthreads();

    const float* WM = ws + NB * H;    // WmlpT[i][k]

    const int row = blockIdx.x * BLOCK + threadIdx.x;

    // ---- h = x @ W_in + b_in : EXACT no-FMA, k ascending, bias after ----
    float h[H];
#pragma unroll
    for (int j = 0; j < H; ++j) h[j] = 0.0f;

    const float4* xr = reinterpret_cast<const float4*>(x + (size_t)row * DM);
    for (int k4 = 0; k4 < DM / 4; ++k4) {
        float4 v = xr[k4];
        const float* w0 = &W_in[(k4 * 4 + 0) * H];
        const float* w1 = &W_in[(k4 * 4 + 1) * H];
        const float* w2 = &W_in[(k4 * 4 + 2) * H];
        const float* w3 = &W_in[(k4 * 4 + 3) * H];
#pragma unroll
        for (int j = 0; j < H; ++j) {
            float a = h[j];
            a = a + v.x * w0[j];
            a = a + v.y * w1[j];
            a = a + v.z * w2[j];
            a = a + v.w * w3[j];
            h[j] = a;
        }
    }
#pragma unroll
    for (int j = 0; j < H; ++j) h[j] = h[j] + b_in[j];

    int* o = out + (size_t)row * DEPTHN;

    for (int d = 0; d < DEPTHN; ++d) {
        // ---- screening bound input: hmax = max_k |h_k| ----
        float hmax = fabsf(h[0]);
#pragma unroll
        for (int k = 1; k < H; ++k) hmax = fmaxf(hmax, fabsf(h[k]));
        const float eps = 4e-5f * hmax + 1e-5f;

        // ---- FMA screen: logits via fmaf, track best + second + index ----
        float best = -INFINITY, second = -INFINITY;
        int bi = 0;
#pragma unroll 2
        for (int p = 0; p < NB / 2; ++p) {
            const float* wr = ws + p * 32;     // [k*2+hh], 128 B uniform
            float a0 = b_out[2 * p];
            float a1 = b_out[2 * p + 1];
#pragma unroll
            for (int k = 0; k < H; ++k) {
                a0 = __builtin_fmaf(h[k], wr[2 * k], a0);
                a1 = __builtin_fmaf(h[k], wr[2 * k + 1], a1);
            }
            {
                bool c = a0 > best;
                float loser = c ? best : a0;
                second = fmaxf(second, loser);
                bi   = c ? 2 * p : bi;
                best = c ? a0    : best;
            }
            {
                bool c = a1 > best;
                float loser = c ? best : a1;
                second = fmaxf(second, loser);
                bi   = c ? 2 * p + 1 : bi;
                best = c ? a1        : best;
            }
        }

        // ---- certified fallback: margin too small -> exact no-FMA argmax ----
        if (best - second <= eps) {
            float bb = -INFINITY;
            int bj = 0;
            for (int j = 0; j < NB; ++j) {
                const float* wr = ws + (j >> 1) * 32 + (j & 1);
                float acc = 0.0f;
#pragma unroll
                for (int k = 0; k < H; ++k) acc = acc + h[k] * wr[2 * k];
                acc = acc + b_out[j];
                if (acc > bb) { bb = acc; bj = j; }
            }
            bi = bj;
        }
        o[d] = bi;

        // ---- h = h + embed[bi] : EXACT ----
        {
            const float4* e = reinterpret_cast<const float4*>(&sEmb[bi * H]);
#pragma unroll
            for (int q4 = 0; q4 < 4; ++q4) {
                float4 ev = e[q4];
                h[q4 * 4 + 0] = h[q4 * 4 + 0] + ev.x;
                h[q4 * 4 + 1] = h[q4 * 4 + 1] + ev.y;
                h[q4 * 4 + 2] = h[q4 * 4 + 2] + ev.z;
                h[q4 * 4 + 3] = h[q4 * 4 + 3] + ev.w;
            }
        }

        // ---- z = h @ W_mlp + b_mlp ; silu : EXACT no-FMA + np-exp ----
        float hn[H];
#pragma unroll
        for (int i = 0; i < H; ++i) {
            const float* wr = &WM[i * H];
            float acc = 0.0f;
#pragma unroll
            for (int k = 0; k < H; ++k) acc = acc + h[k] * wr[k];
            acc = acc + b_mlp[i];
            float e = np_expf(-acc);
            float s = 1.0f / (1.0f + e);
            hn[i] = acc * s;
        }
#pragma unroll
        for (int i = 0; i < H; ++i) h[i] = hn[i];
    }
}

extern "C" void kernel_launch(void* const* d_in, const int* in_sizes, int n_in,
                              void* d_out, int out_size, void* d_ws, size_t ws_size,
                              hipStream_t stream) {
    const float* x     = (const float*)d_in[0];
    const float* W_in  = (const float*)d_in[1];
    const float* b_in  = (const float*)d_in[2];
    const float* embed = (const float*)d_in[3];
    const float* W_mlp = (const float*)d_in[4];
    const float* b_mlp = (const float*)d_in[5];
    const float* W_out = (const float*)d_in[6];
    const float* b_out = (const float*)d_in[7];
    int* out  = (int*)d_out;
    float* ws = (float*)d_ws;          // needs (4096+256)*4 = 17.4 KB

    addrnet_prep_kernel<<<1, 256, 0, stream>>>(W_out, W_mlp, ws);

    dim3 grid(BATCH / BLOCK);          // 2048 blocks, 8192 waves
    dim3 block(BLOCK);
    addrnet_r13_kernel<<<grid, block, 0, stream>>>(x, W_in, b_in, embed,
                                                   b_mlp, b_out, ws, out);
}

// Round 14
// 1050.868 us; speedup vs baseline: 1.0218x; 1.0218x over previous
//
#include <hip/hip_runtime.h>
#include <math.h>

// AddrNet eval forward: B=524288, D_MODEL=128, HID=16, N_BINS=256, DEPTH=8.
// Round 14: R11's proven load/loop structure (pair-interleaved v2f weight
// reads, unroll-2 bin-pair loop, R=1, 8192 waves) with ONE arithmetic change:
// the logits screen uses fmaf from bias (half the insts), certified by the
// R13-validated bound:
//   |L_fma - L_nofma| <= ~8.3e-6*hmax  =>  EPS = 4e-5*hmax + 1e-5 (5x safety)
//   margin > EPS  -> argmax provably equals the no-FMA reference argmax
//   margin <= EPS -> rare exact no-FMA 256-bin recompute (strict >, first-
//                    index ties) — R4 semantics.
// h-trajectory (input layer, embed add, MLP, np-Cephes-exp silu) stays the
// bit-exact no-FMA R4 contract, scalar codegen as in R10.

constexpr int BATCH  = 524288;
constexpr int DM     = 128;
constexpr int H      = 16;
constexpr int NB     = 256;
constexpr int DEPTHN = 8;

constexpr int BLOCK = 256;

typedef float v2f __attribute__((ext_vector_type(2)));

__device__ __forceinline__ float np_expf(float x) {
    // Replica of numpy's SIMD float32 exp (Cephes scheme). Explicit FMAs:
    // part of the verified contract since R4 — do not change.
    const float LOG2E = 1.442695040888963407f;
    const float C1    = 0.693359375f;
    const float C2    = -2.12194440e-4f;
    float q = rintf(x * LOG2E);
    float r = __builtin_fmaf(q, -C1, x);
    r = __builtin_fmaf(q, -C2, r);
    float p = 1.9875691500E-4f;
    p = __builtin_fmaf(p, r, 1.3981999507E-3f);
    p = __builtin_fmaf(p, r, 8.3334519073E-3f);
    p = __builtin_fmaf(p, r, 4.1665795894E-2f);
    p = __builtin_fmaf(p, r, 1.6666665459E-1f);
    p = __builtin_fmaf(p, r, 5.0000001201E-1f);
    p = __builtin_fmaf(p, r * r, r);
    p = p + 1.0f;
    if (x > 88.72283935546875f)      return INFINITY;
    if (x < -103.97208404541015625f) return 0.0f;
    return ldexpf(p, (int)q);
}

// ---- prep (same as R11):
//   ws[p*32 + k*2 + hh] = W_out[k][2p+hh]   p in [0,128)
//   ws[4096 + i*16 + k] = W_mlp[k][i]       (plain transpose, for MLP)
__global__ void addrnet_prep_kernel(const float* __restrict__ W_out,
                                    const float* __restrict__ W_mlp,
                                    float* __restrict__ ws) {
    int t = threadIdx.x;                       // 256 threads, 1 block
    for (int i = t; i < NB * H; i += 256) {
        int p = i >> 5, r = i & 31;
        int k = r >> 1, hh = r & 1;
        ws[i] = W_out[k * NB + (2 * p + hh)];
    }
    {
        int ii = t >> 4, k = t & 15;
        ws[NB * H + ii * H + k] = W_mlp[k * H + ii];
    }
}

__global__ __launch_bounds__(BLOCK, 4) void addrnet_r14_kernel(
    const float* __restrict__ x,      // [B,128]
    const float* __restrict__ W_in,   // [128,16]
    const float* __restrict__ b_in,   // [16]
    const float* __restrict__ embed,  // [256,16]
    const float* __restrict__ b_mlp,  // [16]
    const float* __restrict__ b_out,  // [256]
    const float* __restrict__ ws,     // pair-WP [128][16] v2f ++ WmlpT
    int* __restrict__ out)            // [B,8] int32
{
#pragma clang fp contract(off)
    __shared__ __align__(16) float sEmb[NB * H];    // 16 KB, gather target

    for (int i = threadIdx.x; i < NB * H; i += BLOCK) sEmb[i] = embed[i];
    __syncthreads();

    const v2f* WP  = reinterpret_cast<const v2f*>(ws);          // [p][k] pairs
    const v2f* BO2 = reinterpret_cast<const v2f*>(b_out);       // bin pairs
    const float* WM = ws + NB * H;                              // WmlpT[i][k]

    const int row = blockIdx.x * BLOCK + threadIdx.x;

    // ---- h = x @ W_in + b_in : EXACT no-FMA, k ascending, bias after ----
    float h[H];
#pragma unroll
    for (int j = 0; j < H; ++j) h[j] = 0.0f;

    const float4* xr = reinterpret_cast<const float4*>(x + (size_t)row * DM);
    for (int k4 = 0; k4 < DM / 4; ++k4) {
        float4 v = xr[k4];
        const float* w0 = &W_in[(k4 * 4 + 0) * H];
        const float* w1 = &W_in[(k4 * 4 + 1) * H];
        const float* w2 = &W_in[(k4 * 4 + 2) * H];
        const float* w3 = &W_in[(k4 * 4 + 3) * H];
#pragma unroll
        for (int j = 0; j < H; ++j) {
            float a = h[j];
            a = a + v.x * w0[j];
            a = a + v.y * w1[j];
            a = a + v.z * w2[j];
            a = a + v.w * w3[j];
            h[j] = a;
        }
    }
#pragma unroll
    for (int j = 0; j < H; ++j) h[j] = h[j] + b_in[j];

    int* o = out + (size_t)row * DEPTHN;

    for (int d = 0; d < DEPTHN; ++d) {
        // ---- hmax for the certification bound ----
        float hmax = fabsf(h[0]);
#pragma unroll
        for (int k = 1; k < H; ++k) hmax = fmaxf(hmax, fabsf(h[k]));
        const float eps = 4e-5f * hmax + 1e-5f;

        // ---- FMA screen, R11 load shape: v2f weight pairs, 2 scalar chains.
        //      Track best + second + index. ----
        float best = -INFINITY, second = -INFINITY;
        int bi = 0;
#pragma unroll 2
        for (int p = 0; p < NB / 2; ++p) {
            const v2f* wr = &WP[p * H];        // 16 contiguous 8B pairs
            v2f b2 = BO2[p];
            float a0 = b2.x;
            float a1 = b2.y;
#pragma unroll
            for (int k = 0; k < H; ++k) {
                v2f w = wr[k];
                a0 = __builtin_fmaf(h[k], w.x, a0);
                a1 = __builtin_fmaf(h[k], w.y, a1);
            }
            {
                bool c = a0 > best;
                float loser = c ? best : a0;
                second = fmaxf(second, loser);
                bi   = c ? 2 * p : bi;
                best = c ? a0    : best;
            }
            {
                bool c = a1 > best;
                float loser = c ? best : a1;
                second = fmaxf(second, loser);
                bi   = c ? 2 * p + 1 : bi;
                best = c ? a1        : best;
            }
        }

        // ---- certified fallback: exact no-FMA argmax (rare) ----
        if (best - second <= eps) {
            float bb = -INFINITY;
            int bj = 0;
            for (int p = 0; p < NB / 2; ++p) {
                const v2f* wr = &WP[p * H];
                float acc0 = 0.0f, acc1 = 0.0f;
#pragma unroll
                for (int k = 0; k < H; ++k) {
                    v2f w = wr[k];
                    acc0 = acc0 + h[k] * w.x;   // separate mul+add, k asc
                    acc1 = acc1 + h[k] * w.y;
                }
                v2f b2 = BO2[p];
                acc0 = acc0 + b2.x;
                acc1 = acc1 + b2.y;
                if (acc0 > bb) { bb = acc0; bj = 2 * p; }
                if (acc1 > bb) { bb = acc1; bj = 2 * p + 1; }
            }
            bi = bj;
        }
        o[d] = bi;

        // ---- h = h + embed[bi] : EXACT ----
        {
            const float4* e = reinterpret_cast<const float4*>(&sEmb[bi * H]);
#pragma unroll
            for (int q4 = 0; q4 < 4; ++q4) {
                float4 ev = e[q4];
                h[q4 * 4 + 0] = h[q4 * 4 + 0] + ev.x;
                h[q4 * 4 + 1] = h[q4 * 4 + 1] + ev.y;
                h[q4 * 4 + 2] = h[q4 * 4 + 2] + ev.z;
                h[q4 * 4 + 3] = h[q4 * 4 + 3] + ev.w;
            }
        }

        // ---- z = h @ W_mlp + b_mlp ; silu : EXACT no-FMA + np-exp ----
        float hn[H];
#pragma unroll
        for (int i = 0; i < H; ++i) {
            const float* wr = &WM[i * H];
            float acc = 0.0f;
#pragma unroll
            for (int k = 0; k < H; ++k) acc = acc + h[k] * wr[k];
            acc = acc + b_mlp[i];
            float e = np_expf(-acc);
            float s = 1.0f / (1.0f + e);
            hn[i] = acc * s;
        }
#pragma unroll
        for (int i = 0; i < H; ++i) h[i] = hn[i];
    }
}

extern "C" void kernel_launch(void* const* d_in, const int* in_sizes, int n_in,
                              void* d_out, int out_size, void* d_ws, size_t ws_size,
                              hipStream_t stream) {
    const float* x     = (const float*)d_in[0];
    const float* W_in  = (const float*)d_in[1];
    const float* b_in  = (const float*)d_in[2];
    const float* embed = (const float*)d_in[3];
    const float* W_mlp = (const float*)d_in[4];
    const float* b_mlp = (const float*)d_in[5];
    const float* W_out = (const float*)d_in[6];
    const float* b_out = (const float*)d_in[7];
    int* out  = (int*)d_out;
    float* ws = (float*)d_ws;          // needs (4096+256)*4 = 17.4 KB

    addrnet_prep_kernel<<<1, 256, 0, stream>>>(W_out, W_mlp, ws);

    dim3 grid(BATCH / BLOCK);          // 2048 blocks, 8192 waves
    dim3 block(BLOCK);
    addrnet_r14_kernel<<<grid, block, 0, stream>>>(x, W_in, b_in, embed,
                                                   b_mlp, b_out, ws, out);
}